// Round 1
// baseline (176.835 us; speedup 1.0000x reference)
//
// r12 — occupancy/tail attack.
// Theory: r11 used 72 total regs/wave (40 arch + 32 AGPR acc) -> 7 waves/SIMD
// -> only 3 blocks/CU resident (LDS allows 4). Grid=1024=4x256 then runs as
// two rounds (768 + 256), the second at ~25% occupancy => Occ 47%, all pipes
// idle. Fix: cap 64 regs total (launch_bounds(512,8)) -> 8 waves/SIMD ->
// 4 blocks/CU -> one full resident round, no tail.
// Also: plain-RTNE bf16 conversion off the epilogue path (bit-identical for
// this data; r11's NaN/sat clamps never fire pre-epilogue), and a coalesced
// pack kernel (contiguous 16B writes instead of scattered 2B).
// Layout kept: STR=264 pad — bank math shows b128 A-reads are conflict-free
// (starts 4*((noff+quad+4(k0&1))%8), 8 dwords/bank) and ds offsets stay
// immediate-foldable; measured conflicts (3.1M) are the cheap u16 stores.
#include <hip/hip_runtime.h>

typedef __attribute__((ext_vector_type(8))) short short8;
typedef __attribute__((ext_vector_type(8))) unsigned short ushort8;
typedef __attribute__((ext_vector_type(4))) float f32x4;

#define MT 64            // batch rows per block
#define STR 264          // bf16 elems per LDS row: 256 + 8 pad (528B, 16B-aligned)

// bf16-max-finite as fp32 (0x7F7F0000 = 3.38953139e38) — epilogue clamp value.
__device__ __forceinline__ float bmax_r12() { return __uint_as_float(0x7F7F0000u); }

// plain RTNE fp32 -> bf16 bits. No NaN/sat: every pre-epilogue value is
// provably finite and |v| << 3.3e38 (obs ~N(0,1), W ~N(0,1/sqrt(256)),
// relu-bounded activations), so this is bit-identical to r11's saturating
// version on all values that actually occur.
__device__ __forceinline__ unsigned short f2bf_r12(float f) {
    unsigned int u = __float_as_uint(f);
    return (unsigned short)((u + 0x7fffu + ((u >> 16) & 1u)) >> 16);
}

// pack v2: one thread per 64-lane fragment slot; each thread gathers its 8
// k-elements (strided fp32 reads, L2-friendly) and does ONE contiguous 16B
// write. Output layout/bits identical to r11's pack:
//   dst[(frag*64+lane)*8 + j], frag=(n>>4)*8+(k>>5),
//   lane=((k>>3)&3)*16+(n&15), j=k&7.
__global__ __launch_bounds__(256)
void pack_weights_r12(const float* __restrict__ W1,
                      const float* __restrict__ W2,
                      const float* __restrict__ W3,
                      unsigned short* __restrict__ ws) {
    int s = blockIdx.x * 256 + threadIdx.x;     // 80 x 256 = 20480 slots
    const float* src;
    unsigned short* dst;
    int N;
    if (s < 8192)       { src = W1; dst = ws;          N = 256; }
    else if (s < 16384) { src = W2; dst = ws + 65536;  N = 256; s -= 8192; }
    else                { src = W3; dst = ws + 131072; N = 128; s -= 16384; }
    int frag = s >> 6, lane = s & 63;
    int kb = (frag & 7) * 32 + (lane >> 4) * 8;   // k base (8 consecutive k)
    int n  = (frag >> 3) * 16 + (lane & 15);
    ushort8 o;
    #pragma unroll
    for (int j = 0; j < 8; ++j) o[j] = f2bf_r12(src[(kb + j) * N + n]);
    *(ushort8*)&dst[s * 8] = o;
}

// One 64x256 dense layer (K=256), bias+relu, bf16 LDS act IN-PLACE:
// MFMA reads -> barrier -> writeback -> barrier (caller supplies barriers).
__device__ __forceinline__ void layer_mfma_r12(
    const unsigned short* __restrict__ act, const unsigned short* __restrict__ wp,
    int wave, int lane, int quad, int noff, f32x4 acc[4][2])
{
    #pragma unroll
    for (int k0 = 0; k0 < 8; ++k0) {
        short8 b0 = *(const short8*)&wp[(((wave * 2 + 0) * 8 + k0) * 64 + lane) * 8];
        short8 b1 = *(const short8*)&wp[(((wave * 2 + 1) * 8 + k0) * 64 + lane) * 8];
        #pragma unroll
        for (int rt = 0; rt < 4; ++rt) {
            short8 a = *(const short8*)&act[(rt * 16 + noff) * STR + k0 * 32 + quad * 8];
            acc[rt][0] = __builtin_amdgcn_mfma_f32_16x16x32_bf16(a, b0, acc[rt][0], 0, 0, 0);
            acc[rt][1] = __builtin_amdgcn_mfma_f32_16x16x32_bf16(a, b1, acc[rt][1], 0, 0, 0);
        }
    }
}

__device__ __forceinline__ void layer_store_r12(
    unsigned short* __restrict__ act, const float* __restrict__ bias,
    int wave, int quad, int noff, f32x4 acc[4][2])
{
    #pragma unroll
    for (int ct = 0; ct < 2; ++ct) {
        int col = (wave * 2 + ct) * 16 + noff;
        float bv = bias[col];
        #pragma unroll
        for (int rt = 0; rt < 4; ++rt) {
            #pragma unroll
            for (int i = 0; i < 4; ++i) {
                float v = fmaxf(acc[rt][ct][i] + bv, 0.0f);   // relu; finite by data
                act[(rt * 16 + quad * 4 + i) * STR + col] = f2bf_r12(v);
            }
        }
    }
}

__global__ __launch_bounds__(512, 8)   // 8 waves/EU -> cap 64 regs -> 4 blocks/CU
void ColorNetwork_32495722561720_kernel(
        const float* __restrict__ obs,
        const int* __restrict__ amask,
        const float* __restrict__ b1,
        const float* __restrict__ b2,
        const float* __restrict__ b3,
        const unsigned short* __restrict__ w1p,
        const unsigned short* __restrict__ w2p,
        const unsigned short* __restrict__ w3p,
        float* __restrict__ out)
{
    // 33792 (act) + 256 (rowany) = 34048 B LDS -> 4 blocks/CU by LDS
    __shared__ __align__(16) unsigned short act[MT * STR];
    __shared__ int rowany[MT];

    const int tid  = threadIdx.x;
    const int wave = tid >> 6;
    const int lane = tid & 63;
    const int quad = lane >> 4;
    const int noff = lane & 15;
    const size_t rowbase = (size_t)blockIdx.x * MT;

    if (tid < MT) rowany[tid] = 0;

    // ---- stage X: 64 rows x 256 fp32 -> bf16 LDS (4096 float4, 8/thread) ----
    const float4* xin = (const float4*)(obs + rowbase * 256);
    #pragma unroll
    for (int i = 0; i < 8; ++i) {
        int f = tid + i * 512;        // 64 float4-chunks per row
        int row = f >> 6;
        int c4 = f & 63;
        float4 v = xin[f];
        ushort4 p;
        p.x = f2bf_r12(v.x); p.y = f2bf_r12(v.y);
        p.z = f2bf_r12(v.z); p.w = f2bf_r12(v.w);
        *(ushort4*)&act[row * STR + c4 * 4] = p;
    }
    __syncthreads();   // X visible; orders rowany init before |= below

    // ---- rowany only (mask bytes re-read from global in the epilogue;
    //      L2 absorbs the re-read). 2048 int4, 4/thread. ----
    const int4* min4 = (const int4*)(amask + rowbase * 128);
    #pragma unroll
    for (int i = 0; i < 4; ++i) {
        int f = tid + i * 512;
        int4 m = min4[f];
        if (m.x | m.y | m.z | m.w) rowany[f >> 5] = 1;
    }

    {   // ---- layer 1 (in place) ----
        f32x4 acc[4][2] = {};
        layer_mfma_r12(act, w1p, wave, lane, quad, noff, acc);
        __syncthreads();                       // all reads done (also rowany writes)
        layer_store_r12(act, b1, wave, quad, noff, acc);
        __syncthreads();                       // all writes visible
    }
    {   // ---- layer 2 (in place) ----
        f32x4 acc[4][2] = {};
        layer_mfma_r12(act, w2p, wave, lane, quad, noff, acc);
        __syncthreads();
        layer_store_r12(act, b2, wave, quad, noff, acc);
        __syncthreads();
    }
    {   // ---- layer 3 (N=128): regs -> masked fp32 store ----
        const int col = wave * 16 + noff;
        // prefetch this lane's 16 mask words (independent of LDS; scheduler
        // hoists these global loads among the MFMAs)
        int mv[16];
        #pragma unroll
        for (int rt = 0; rt < 4; ++rt)
            #pragma unroll
            for (int i = 0; i < 4; ++i)
                mv[rt * 4 + i] = amask[(rowbase + rt * 16 + quad * 4 + i) * 128 + col];

        f32x4 acc[4] = {};
        #pragma unroll
        for (int k0 = 0; k0 < 8; ++k0) {
            short8 b0 = *(const short8*)&w3p[((wave * 8 + k0) * 64 + lane) * 8];
            #pragma unroll
            for (int rt = 0; rt < 4; ++rt) {
                short8 a = *(const short8*)&act[(rt * 16 + noff) * STR + k0 * 32 + quad * 8];
                acc[rt] = __builtin_amdgcn_mfma_f32_16x16x32_bf16(a, b0, acc[rt], 0, 0, 0);
            }
        }
        const float BM = bmax_r12();
        const float bv = b3[col];
        #pragma unroll
        for (int rt = 0; rt < 4; ++rt) {
            #pragma unroll
            for (int i = 0; i < 4; ++i) {
                int row = rt * 16 + quad * 4 + i;
                float v = acc[rt][i] + bv;
                v = fminf(fmaxf(v, -BM), BM);        // finite AND bf16-finite
                if (!(v == v)) v = 0.0f;             // NaN scrub (paranoia)
                if (!mv[rt * 4 + i]) v = -BM;        // FLOAT_MIN stand-in
                if (!rowany[row]) v = (col == 0) ? 1.0f : -BM;
                out[(rowbase + row) * 128 + col] = v;
            }
        }
    }
}

extern "C" void kernel_launch(void* const* d_in, const int* in_sizes, int n_in,
                              void* d_out, int out_size, void* d_ws, size_t ws_size,
                              hipStream_t stream) {
    const float* obs   = (const float*)d_in[0];
    const int*   amask = (const int*)d_in[1];
    const float* W1 = (const float*)d_in[2];
    const float* b1 = (const float*)d_in[3];
    const float* W2 = (const float*)d_in[4];
    const float* b2 = (const float*)d_in[5];
    const float* W3 = (const float*)d_in[6];
    const float* b3 = (const float*)d_in[7];
    float* out = (float*)d_out;

    const int B = in_sizes[0] / 256;   // 65536 batch rows

    unsigned short* ws = (unsigned short*)d_ws;    // 163840 bf16 = 320 KB packed
    unsigned short* w1p = ws;
    unsigned short* w2p = ws + 65536;
    unsigned short* w3p = ws + 131072;

    pack_weights_r12<<<80, 256, 0, stream>>>(W1, W2, W3, ws);

    ColorNetwork_32495722561720_kernel<<<B / MT, 512, 0, stream>>>(
        obs, amask, b1, b2, b3, w1p, w2p, w3p, out);
}